// Round 2
// baseline (127.046 us; speedup 1.0000x reference)
//
#include <hip/hip_runtime.h>
#include <math.h>

#define BATCH 256
#define KSNIP 32
#define CH    2048
#define CH4   512
#define NCLSS 20

// ---- ws layout (floats) ----
#define OFF_MNA 0               // [256][2048] meanNA
#define OFF_MNB 524288          // [256][2048] meanNB
#define OFF_PK  1048576         // 7 arrays of [256*32]:
                                // j=0 dot(meanNA,PB_k)  j=1 ||PB_k||^2
                                // j=2 dot(meanNB,PA_k)  j=3 ||PA_k||^2
                                // j=4 rowsum(PA_k)      j=5 dot(meanNA,PA_k)
                                // j=6 dot(meanNB,PB_k)
#define PKN 8192
#define OFF_SC  1105920         // n2PA[256], n2PB[256], n2NA[256], n2NB[256]

__device__ __forceinline__ float dot4(float4 a, float4 b) {
    return a.x*b.x + a.y*b.y + a.z*b.z + a.w*b.w;
}
__device__ __forceinline__ float sum4(float4 a) { return a.x + a.y + a.z + a.w; }
__device__ __forceinline__ float4 add4(float4 a, float4 b) {
    return make_float4(a.x+b.x, a.y+b.y, a.z+b.z, a.w+b.w);
}

// K1: one block per (tensor t, video b). Pure streaming mean over K.
// t order: 0=NA,1=NB,2=PA,3=PB so PA/PB are streamed last (L3-warm for K2).
__global__ __launch_bounds__(512) void mean_kernel(
    const float* __restrict__ PA, const float* __restrict__ PB,
    const float* __restrict__ NAp, const float* __restrict__ NBp,
    float* __restrict__ ws)
{
    const int t   = blockIdx.x >> 8;
    const int b   = blockIdx.x & 255;
    const int tid = threadIdx.x;

    const float* srcs[4] = {NAp, NBp, PA, PB};
    const float4* src = (const float4*)(srcs[t] + (size_t)b * KSNIP * CH);

    float4 a0 = {0,0,0,0}, a1 = {0,0,0,0}, a2 = {0,0,0,0}, a3 = {0,0,0,0};
    #pragma unroll
    for (int k = 0; k < KSNIP; k += 4) {
        a0 = add4(a0, src[(k+0)*CH4 + tid]);
        a1 = add4(a1, src[(k+1)*CH4 + tid]);
        a2 = add4(a2, src[(k+2)*CH4 + tid]);
        a3 = add4(a3, src[(k+3)*CH4 + tid]);
    }
    float4 m = add4(add4(a0,a1), add4(a2,a3));
    const float s = 1.0f/32.0f;
    m.x *= s; m.y *= s; m.z *= s; m.w *= s;

    if (t == 0) ((float4*)(ws + OFF_MNA + b*CH))[tid] = m;
    if (t == 1) ((float4*)(ws + OFF_MNB + b*CH))[tid] = m;

    // ||mean||^2 block reduction
    float v = dot4(m, m);
    #pragma unroll
    for (int o = 32; o; o >>= 1) v += __shfl_xor(v, o);
    __shared__ float sw[8];
    if ((tid & 63) == 0) sw[tid >> 6] = v;
    __syncthreads();
    if (tid == 0) {
        float tot = 0.f;
        #pragma unroll
        for (int w = 0; w < 8; ++w) tot += sw[w];
        const int sc_map[4] = {2, 3, 0, 1};   // NA->n2NA(2), NB->3, PA->0, PB->1
        ws[OFF_SC + sc_map[t]*256 + b] = tot;
    }
}

// K2: block = (video b, half h). Wave handles 2 k's; lanes sweep channels.
__global__ __launch_bounds__(512) void dots_kernel(
    const float* __restrict__ PA, const float* __restrict__ PB,
    float* __restrict__ ws)
{
    const int b    = blockIdx.x >> 1;
    const int h    = blockIdx.x & 1;
    const int tid  = threadIdx.x;
    const int wave = tid >> 6;
    const int lane = tid & 63;

    __shared__ float4 sNA[CH4];
    __shared__ float4 sNB[CH4];
    sNA[tid] = ((const float4*)(ws + OFF_MNA + b*CH))[tid];
    sNB[tid] = ((const float4*)(ws + OFF_MNB + b*CH))[tid];
    __syncthreads();

    const float4* PAb = (const float4*)(PA + (size_t)b * KSNIP * CH);
    const float4* PBb = (const float4*)(PB + (size_t)b * KSNIP * CH);

    #pragma unroll
    for (int kk = 0; kk < 2; ++kk) {
        const int k = h*16 + wave*2 + kk;
        const float4* pa = PAb + k*CH4;
        const float4* pb = PBb + k*CH4;
        float d0=0.f,d1=0.f,d2=0.f,d3=0.f,d4=0.f,d5=0.f,d6=0.f;
        #pragma unroll
        for (int ss = 0; ss < 8; ++ss) {
            const int c4 = lane + ss*64;
            float4 va = pa[c4];
            float4 vb = pb[c4];
            float4 na = sNA[c4];
            float4 nb = sNB[c4];
            d0 += dot4(na, vb);
            d1 += dot4(vb, vb);
            d2 += dot4(nb, va);
            d3 += dot4(va, va);
            d4 += sum4(va);
            d5 += dot4(na, va);
            d6 += dot4(nb, vb);
        }
        #pragma unroll
        for (int o = 32; o; o >>= 1) {
            d0 += __shfl_xor(d0, o);
            d1 += __shfl_xor(d1, o);
            d2 += __shfl_xor(d2, o);
            d3 += __shfl_xor(d3, o);
            d4 += __shfl_xor(d4, o);
            d5 += __shfl_xor(d5, o);
            d6 += __shfl_xor(d6, o);
        }
        if (lane == 0) {
            const int idx = b*KSNIP + k;
            ws[OFF_PK + 0*PKN + idx] = d0;
            ws[OFF_PK + 1*PKN + idx] = d1;
            ws[OFF_PK + 2*PKN + idx] = d2;
            ws[OFF_PK + 3*PKN + idx] = d3;
            ws[OFF_PK + 4*PKN + idx] = d4;
            ws[OFF_PK + 5*PKN + idx] = d5;
            ws[OFF_PK + 6*PKN + idx] = d6;
        }
    }
}

// K3: single block, 256 threads (thread == video b). Finishes all losses.
__global__ __launch_bounds__(256) void finish_kernel(
    const float* __restrict__ vs, const float* __restrict__ label,
    const float* __restrict__ ws, float* __restrict__ out)
{
    const int tid = threadIdx.x;
    const int b   = tid;

    __shared__ float an[BATCH][33];
    __shared__ float sbuf[4];
    __shared__ float sred[4][3];
    __shared__ int   s_anchor, s_cnt;

    const float* pk   = ws + OFF_PK;
    const float* n2PA = ws + OFF_SC + 0*256;
    const float* n2PB = ws + OFF_SC + 1*256;
    const float* n2NA = ws + OFF_SC + 2*256;
    const float* n2NB = ws + OFF_SC + 3*256;

    const float invT = 1.0f / 0.07f;
    const float nPA = sqrtf(n2PA[b]);
    const float nPB = sqrtf(n2PB[b]);
    const float nNA = sqrtf(n2NA[b]);
    const float nNB = sqrtf(n2NB[b]);

    // l_pos dots: dot(meanNA, meanPA) = mean_k dot(meanNA, PA_k); same for B
    float dAP = 0.f, dBP = 0.f;
    for (int k = 0; k < KSNIP; ++k) {
        dAP += pk[5*PKN + b*KSNIP + k];
        dBP += pk[6*PKN + b*KSNIP + k];
    }
    dAP *= (1.0f/32.0f);
    dBP *= (1.0f/32.0f);

    // NCE 1: q=meanNA, k=meanPA, neg=PB
    float nce;
    {
        float lpos = dAP / (nNA * nPA) * invT;
        float m = lpos, s = 1.0f;
        for (int k = 0; k < KSNIP; ++k) {
            float v = pk[0*PKN + b*KSNIP + k] / (nNA * sqrtf(pk[1*PKN + b*KSNIP + k])) * invT;
            if (v > m) { s = s * expf(m - v) + 1.0f; m = v; }
            else       { s += expf(v - m); }
        }
        nce = (logf(s) + m) - lpos;
    }
    // NCE 2: q=meanNB, k=meanPB, neg=PA
    {
        float lpos = dBP / (nNB * nPB) * invT;
        float m = lpos, s = 1.0f;
        for (int k = 0; k < KSNIP; ++k) {
            float v = pk[2*PKN + b*KSNIP + k] / (nNB * sqrtf(pk[3*PKN + b*KSNIP + k])) * invT;
            if (v > m) { s = s * expf(m - v) + 1.0f; m = v; }
            else       { s += expf(v - m); }
        }
        nce += (logf(s) + m) - lpos;
    }

    // abs loss
    float la   = fmaxf(150.0f - nPA, 0.0f);
    float absb = (la + nPB) * (la + nPB);

    // BCE with row-normalized labels
    float rs = 0.0f;
    for (int c = 0; c < NCLSS; ++c) rs += label[b*NCLSS + c];
    float clsb = 0.0f;
    for (int c = 0; c < NCLSS; ++c) {
        float l = label[b*NCLSS + c] / rs;
        float p = vs[b*NCLSS + c];
        clsb -= l * logf(p) + (1.0f - l) * logf(1.0f - p);
    }

    auto blocksum = [&](float v) -> float {
        #pragma unroll
        for (int o = 32; o; o >>= 1) v += __shfl_xor(v, o);
        __syncthreads();
        if ((tid & 63) == 0) sbuf[tid >> 6] = v;
        __syncthreads();
        return sbuf[0] + sbuf[1] + sbuf[2] + sbuf[3];
    };

    const float loss_snico = blocksum(nce)  / 256.0f;
    const float loss_abs   = blocksum(absb) / 256.0f;
    const float loss_cls   = blocksum(clsb) / 5120.0f;

    // ---- triplet ----
    // act[b][k] = rowsum(PA_k)/2048; uniform row scale cancels under
    // normalization, so use rowsum directly.
    for (int i = tid; i < BATCH*KSNIP; i += BATCH)
        an[i >> 5][i & 31] = pk[4*PKN + i];
    __syncthreads();
    {
        float nrm = 0.0f;
        #pragma unroll
        for (int k = 0; k < KSNIP; ++k) { float v = an[b][k]; nrm += v * v; }
        float inv = 1.0f / sqrtf(nrm);
        #pragma unroll
        for (int k = 0; k < KSNIP; ++k) an[b][k] *= inv;
    }

    float trip_total = 0.0f;
    for (int c = 0; c < NCLSS; ++c) {
        __syncthreads();
        if (tid == 0) { s_anchor = -1; s_cnt = 0; }
        __syncthreads();
        const bool mm = label[b*NCLSS + c] > 0.5f;
        if (mm) { atomicMax(&s_anchor, b); atomicAdd(&s_cnt, 1); }
        __syncthreads();
        const int cnt = s_cnt, anchor = s_anchor;
        if (cnt > 1) {
            float dacc = 0.0f;
            #pragma unroll
            for (int k = 0; k < KSNIP; ++k) dacc += an[anchor][k] * an[b][k];
            const float d = 1.0f - dacc;
            float vAll = d;
            float vMem = (mm && b != anchor) ? d : -__builtin_inff();
            float vNon = (!mm) ? d : __builtin_inff();
            #pragma unroll
            for (int o = 32; o; o >>= 1) {
                vAll = fmaxf(vAll, __shfl_xor(vAll, o));
                vMem = fmaxf(vMem, __shfl_xor(vMem, o));
                vNon = fminf(vNon, __shfl_xor(vNon, o));
            }
            if ((tid & 63) == 0) {
                int w = tid >> 6;
                sred[w][0] = vAll; sred[w][1] = vMem; sred[w][2] = vNon;
            }
            __syncthreads();
            if (tid == 0) {
                float maxAll = fmaxf(fmaxf(sred[0][0], sred[1][0]), fmaxf(sred[2][0], sred[3][0]));
                float maxMem = fmaxf(fmaxf(sred[0][1], sred[1][1]), fmaxf(sred[2][1], sred[3][1]));
                float minNon = fminf(fminf(sred[0][2], sred[1][2]), fminf(sred[2][2], sred[3][2]));
                float max_d = fmaxf(0.0f, maxMem);
                float min_d = fminf(maxAll, minNon);
                trip_total += fmaxf(max_d - min_d + 0.8f, 0.0f);
            }
        }
    }

    if (tid == 0) {
        float total = loss_cls + 0.01f * loss_snico + 0.0005f * loss_abs + 0.005f * trip_total;
        out[0] = total;
        out[1] = loss_cls;
        out[2] = loss_snico;
        out[3] = loss_abs;
        out[4] = trip_total;
    }
}

extern "C" void kernel_launch(void* const* d_in, const int* in_sizes, int n_in,
                              void* d_out, int out_size, void* d_ws, size_t ws_size,
                              hipStream_t stream) {
    const float* vs    = (const float*)d_in[0];
    const float* label = (const float*)d_in[1];
    const float* PA    = (const float*)d_in[2];
    const float* PB    = (const float*)d_in[3];
    const float* NAp   = (const float*)d_in[4];
    const float* NBp   = (const float*)d_in[5];
    float* ws  = (float*)d_ws;
    float* out = (float*)d_out;

    mean_kernel  <<<dim3(4*BATCH), dim3(512), 0, stream>>>(PA, PB, NAp, NBp, ws);
    dots_kernel  <<<dim3(2*BATCH), dim3(512), 0, stream>>>(PA, PB, ws);
    finish_kernel<<<dim3(1),       dim3(256), 0, stream>>>(vs, label, ws, out);
}

// Round 3
// 112.774 us; speedup vs baseline: 1.1265x; 1.1265x over previous
//
#include <hip/hip_runtime.h>
#include <math.h>

#define BATCH 256
#define KSNIP 32
#define CH    2048
#define CH4   512
#define NCLSS 20

// ---- ws layout (floats) ----
#define OFF_MNA 0               // [256][2048] meanNA
#define OFF_MNB 524288          // [256][2048] meanNB
#define OFF_PK  1048576         // 5 arrays of [256*32]:
                                // j=0 dot(meanNA,PB_k)  j=1 ||PB_k||^2
                                // j=2 dot(meanNB,PA_k)  j=3 ||PA_k||^2
                                // j=4 rowsum(PA_k)
#define PKN 8192
#define OFF_SC  1089536         // 0:n2PA 1:n2PB 2:n2NA 3:n2NB 4:dAP 5:dBP (each [256])

__device__ __forceinline__ float dot4(float4 a, float4 b) {
    return a.x*b.x + a.y*b.y + a.z*b.z + a.w*b.w;
}
__device__ __forceinline__ float sum4(float4 a) { return a.x + a.y + a.z + a.w; }
__device__ __forceinline__ float4 add4(float4 a, float4 b) {
    return make_float4(a.x+b.x, a.y+b.y, a.z+b.z, a.w+b.w);
}

// K1: block (t,b), t=0:NA t=1:NB. Wave w reads whole k-rows (8KB contiguous)
// for k = w + 8*kk; batch of 8 independent float4 loads per row.
// Produces meanNA/meanNB vectors + n2NA/n2NB.
__global__ __launch_bounds__(512) void meanNK_kernel(
    const float* __restrict__ NAp, const float* __restrict__ NBp,
    float* __restrict__ ws)
{
    const int t   = blockIdx.x >> 8;
    const int b   = blockIdx.x & 255;
    const int tid = threadIdx.x;
    const int w   = tid >> 6;
    const int l   = tid & 63;

    const float4* src = (const float4*)((t ? NBp : NAp) + (size_t)b * KSNIP * CH);

    float4 cs[8];
    #pragma unroll
    for (int j = 0; j < 8; ++j) cs[j] = make_float4(0.f,0.f,0.f,0.f);

    #pragma unroll
    for (int kk = 0; kk < 4; ++kk) {
        const int k = w + kk*8;
        float4 v[8];
        #pragma unroll
        for (int j = 0; j < 8; ++j) v[j] = src[k*CH4 + l + j*64];
        #pragma unroll
        for (int j = 0; j < 8; ++j) cs[j] = add4(cs[j], v[j]);
    }

    // cross-wave column sums
    __shared__ float4 sCol[CH4];
    __shared__ float  sW[8];
    for (int wv = 0; wv < 8; ++wv) {
        if (w == wv) {
            #pragma unroll
            for (int j = 0; j < 8; ++j) {
                const int c = l + j*64;
                sCol[c] = (wv == 0) ? cs[j] : add4(sCol[c], cs[j]);
            }
        }
        __syncthreads();
    }

    float4 m = sCol[tid];
    const float s = 1.0f/32.0f;
    m.x *= s; m.y *= s; m.z *= s; m.w *= s;
    ((float4*)(ws + (t ? OFF_MNB : OFF_MNA) + b*CH))[tid] = m;

    float v2 = dot4(m, m);
    #pragma unroll
    for (int o = 32; o; o >>= 1) v2 += __shfl_xor(v2, o);
    if (l == 0) sW[w] = v2;
    __syncthreads();
    if (tid == 0) {
        float tot = 0.f;
        #pragma unroll
        for (int i = 0; i < 8; ++i) tot += sW[i];
        ws[OFF_SC + (2 + t)*256 + b] = tot;   // 2:n2NA 3:n2NB
    }
}

// K2: block (t,b), t=0:PA t=1:PB. Per k-row: dot vs the paired N-mean,
// sumsq, rowsum (PA only); plus column k-sums -> meanP norm^2 and dAP/dBP.
__global__ __launch_bounds__(512) void dots_kernel(
    const float* __restrict__ PA, const float* __restrict__ PB,
    float* __restrict__ ws)
{
    const int t   = blockIdx.x >> 8;
    const int b   = blockIdx.x & 255;
    const int tid = threadIdx.x;
    const int w   = tid >> 6;
    const int l   = tid & 63;

    const float4* src = (const float4*)((t ? PB : PA) + (size_t)b * KSNIP * CH);

    __shared__ float4 sDot[CH4];   // mean for per-k dot: PA->meanNB, PB->meanNA
    __shared__ float4 sDap[CH4];   // mean for l_pos dot: PA->meanNA, PB->meanNB
    __shared__ float4 sCol[CH4];
    __shared__ float  sW[8][2];

    sDot[tid] = ((const float4*)(ws + (t ? OFF_MNA : OFF_MNB)))[b*CH4 + tid];
    sDap[tid] = ((const float4*)(ws + (t ? OFF_MNB : OFF_MNA)))[b*CH4 + tid];
    __syncthreads();

    float4 cs[8];
    #pragma unroll
    for (int j = 0; j < 8; ++j) cs[j] = make_float4(0.f,0.f,0.f,0.f);

    #pragma unroll
    for (int kk = 0; kk < 4; ++kk) {
        const int k = w + kk*8;
        float4 v[8];
        #pragma unroll
        for (int j = 0; j < 8; ++j) v[j] = src[k*CH4 + l + j*64];

        float dq = 0.f, sq = 0.f, rs = 0.f;
        #pragma unroll
        for (int j = 0; j < 8; ++j) {
            cs[j] = add4(cs[j], v[j]);
            float4 om = sDot[l + j*64];
            dq += dot4(om, v[j]);
            sq += dot4(v[j], v[j]);
            rs += sum4(v[j]);
        }
        #pragma unroll
        for (int o = 32; o; o >>= 1) {
            dq += __shfl_xor(dq, o);
            sq += __shfl_xor(sq, o);
            rs += __shfl_xor(rs, o);
        }
        if (l == 0) {
            const int idx = b*KSNIP + k;
            if (t == 0) {   // PA
                ws[OFF_PK + 2*PKN + idx] = dq;
                ws[OFF_PK + 3*PKN + idx] = sq;
                ws[OFF_PK + 4*PKN + idx] = rs;
            } else {        // PB
                ws[OFF_PK + 0*PKN + idx] = dq;
                ws[OFF_PK + 1*PKN + idx] = sq;
            }
        }
    }

    // cross-wave column k-sums
    for (int wv = 0; wv < 8; ++wv) {
        if (w == wv) {
            #pragma unroll
            for (int j = 0; j < 8; ++j) {
                const int c = l + j*64;
                sCol[c] = (wv == 0) ? cs[j] : add4(sCol[c], cs[j]);
            }
        }
        __syncthreads();
    }

    float4 m = sCol[tid];
    const float s = 1.0f/32.0f;
    m.x *= s; m.y *= s; m.z *= s; m.w *= s;
    float n2  = dot4(m, m);
    float dap = dot4(sDap[tid], m);
    #pragma unroll
    for (int o = 32; o; o >>= 1) {
        n2  += __shfl_xor(n2, o);
        dap += __shfl_xor(dap, o);
    }
    if (l == 0) { sW[w][0] = n2; sW[w][1] = dap; }
    __syncthreads();
    if (tid == 0) {
        float t0 = 0.f, t1 = 0.f;
        #pragma unroll
        for (int i = 0; i < 8; ++i) { t0 += sW[i][0]; t1 += sW[i][1]; }
        ws[OFF_SC + t*256 + b]       = t0;   // 0:n2PA 1:n2PB
        ws[OFF_SC + (4 + t)*256 + b] = t1;   // 4:dAP  5:dBP
    }
}

// K3: single block, 256 threads (thread == video b). Finishes all losses.
__global__ __launch_bounds__(256) void finish_kernel(
    const float* __restrict__ vs, const float* __restrict__ label,
    const float* __restrict__ ws, float* __restrict__ out)
{
    const int tid = threadIdx.x;
    const int b   = tid;

    __shared__ float an[BATCH][33];
    __shared__ float sbuf[4];
    __shared__ float sred[4][3];
    __shared__ int   s_anchor, s_cnt;

    const float* pk   = ws + OFF_PK;
    const float* n2PA = ws + OFF_SC + 0*256;
    const float* n2PB = ws + OFF_SC + 1*256;
    const float* n2NA = ws + OFF_SC + 2*256;
    const float* n2NB = ws + OFF_SC + 3*256;

    const float invT = 1.0f / 0.07f;
    const float nPA = sqrtf(n2PA[b]);
    const float nPB = sqrtf(n2PB[b]);
    const float nNA = sqrtf(n2NA[b]);
    const float nNB = sqrtf(n2NB[b]);

    const float dAP = ws[OFF_SC + 4*256 + b];
    const float dBP = ws[OFF_SC + 5*256 + b];

    // NCE 1: q=meanNA, k=meanPA, neg=PB
    float nce;
    {
        float lpos = dAP / (nNA * nPA) * invT;
        float m = lpos, s = 1.0f;
        for (int k = 0; k < KSNIP; ++k) {
            float v = pk[0*PKN + b*KSNIP + k] / (nNA * sqrtf(pk[1*PKN + b*KSNIP + k])) * invT;
            if (v > m) { s = s * expf(m - v) + 1.0f; m = v; }
            else       { s += expf(v - m); }
        }
        nce = (logf(s) + m) - lpos;
    }
    // NCE 2: q=meanNB, k=meanPB, neg=PA
    {
        float lpos = dBP / (nNB * nPB) * invT;
        float m = lpos, s = 1.0f;
        for (int k = 0; k < KSNIP; ++k) {
            float v = pk[2*PKN + b*KSNIP + k] / (nNB * sqrtf(pk[3*PKN + b*KSNIP + k])) * invT;
            if (v > m) { s = s * expf(m - v) + 1.0f; m = v; }
            else       { s += expf(v - m); }
        }
        nce += (logf(s) + m) - lpos;
    }

    // abs loss
    float la   = fmaxf(150.0f - nPA, 0.0f);
    float absb = (la + nPB) * (la + nPB);

    // BCE with row-normalized labels
    float rs = 0.0f;
    for (int c = 0; c < NCLSS; ++c) rs += label[b*NCLSS + c];
    float clsb = 0.0f;
    for (int c = 0; c < NCLSS; ++c) {
        float l = label[b*NCLSS + c] / rs;
        float p = vs[b*NCLSS + c];
        clsb -= l * logf(p) + (1.0f - l) * logf(1.0f - p);
    }

    auto blocksum = [&](float v) -> float {
        #pragma unroll
        for (int o = 32; o; o >>= 1) v += __shfl_xor(v, o);
        __syncthreads();
        if ((tid & 63) == 0) sbuf[tid >> 6] = v;
        __syncthreads();
        return sbuf[0] + sbuf[1] + sbuf[2] + sbuf[3];
    };

    const float loss_snico = blocksum(nce)  / 256.0f;
    const float loss_abs   = blocksum(absb) / 256.0f;
    const float loss_cls   = blocksum(clsb) / 5120.0f;

    // ---- triplet (act = rowsum/2048; uniform scale cancels under norm) ----
    for (int i = tid; i < BATCH*KSNIP; i += BATCH)
        an[i >> 5][i & 31] = pk[4*PKN + i];
    __syncthreads();
    {
        float nrm = 0.0f;
        #pragma unroll
        for (int k = 0; k < KSNIP; ++k) { float v = an[b][k]; nrm += v * v; }
        float inv = 1.0f / sqrtf(nrm);
        #pragma unroll
        for (int k = 0; k < KSNIP; ++k) an[b][k] *= inv;
    }

    float trip_total = 0.0f;
    for (int c = 0; c < NCLSS; ++c) {
        __syncthreads();
        if (tid == 0) { s_anchor = -1; s_cnt = 0; }
        __syncthreads();
        const bool mm = label[b*NCLSS + c] > 0.5f;
        if (mm) { atomicMax(&s_anchor, b); atomicAdd(&s_cnt, 1); }
        __syncthreads();
        const int cnt = s_cnt, anchor = s_anchor;
        if (cnt > 1) {
            float dacc = 0.0f;
            #pragma unroll
            for (int k = 0; k < KSNIP; ++k) dacc += an[anchor][k] * an[b][k];
            const float d = 1.0f - dacc;
            float vAll = d;
            float vMem = (mm && b != anchor) ? d : -__builtin_inff();
            float vNon = (!mm) ? d : __builtin_inff();
            #pragma unroll
            for (int o = 32; o; o >>= 1) {
                vAll = fmaxf(vAll, __shfl_xor(vAll, o));
                vMem = fmaxf(vMem, __shfl_xor(vMem, o));
                vNon = fminf(vNon, __shfl_xor(vNon, o));
            }
            if ((tid & 63) == 0) {
                int w = tid >> 6;
                sred[w][0] = vAll; sred[w][1] = vMem; sred[w][2] = vNon;
            }
            __syncthreads();
            if (tid == 0) {
                float maxAll = fmaxf(fmaxf(sred[0][0], sred[1][0]), fmaxf(sred[2][0], sred[3][0]));
                float maxMem = fmaxf(fmaxf(sred[0][1], sred[1][1]), fmaxf(sred[2][1], sred[3][1]));
                float minNon = fminf(fminf(sred[0][2], sred[1][2]), fminf(sred[2][2], sred[3][2]));
                float max_d = fmaxf(0.0f, maxMem);
                float min_d = fminf(maxAll, minNon);
                trip_total += fmaxf(max_d - min_d + 0.8f, 0.0f);
            }
        }
    }

    if (tid == 0) {
        float total = loss_cls + 0.01f * loss_snico + 0.0005f * loss_abs + 0.005f * trip_total;
        out[0] = total;
        out[1] = loss_cls;
        out[2] = loss_snico;
        out[3] = loss_abs;
        out[4] = trip_total;
    }
}

extern "C" void kernel_launch(void* const* d_in, const int* in_sizes, int n_in,
                              void* d_out, int out_size, void* d_ws, size_t ws_size,
                              hipStream_t stream) {
    const float* vs    = (const float*)d_in[0];
    const float* label = (const float*)d_in[1];
    const float* PA    = (const float*)d_in[2];
    const float* PB    = (const float*)d_in[3];
    const float* NAp   = (const float*)d_in[4];
    const float* NBp   = (const float*)d_in[5];
    float* ws  = (float*)d_ws;
    float* out = (float*)d_out;

    meanNK_kernel<<<dim3(512), dim3(512), 0, stream>>>(NAp, NBp, ws);
    dots_kernel  <<<dim3(512), dim3(512), 0, stream>>>(PA, PB, ws);
    finish_kernel<<<dim3(1),   dim3(256), 0, stream>>>(vs, label, ws, out);
}

// Round 4
// 85.136 us; speedup vs baseline: 1.4923x; 1.3246x over previous
//
#include <hip/hip_runtime.h>
#include <math.h>

#define BATCH 256
#define KSNIP 32
#define CH    2048
#define CH4   512
#define NCLSS 20

// ---- ws layout (floats) ----
#define OFF_MNA 0               // [256][2048] meanNA
#define OFF_MNB 524288          // [256][2048] meanNB
#define OFF_PK  1048576         // 5 arrays, K-MAJOR [k*256+b]:
                                // j=0 dot(meanNA,PB_k)  j=1 ||PB_k||^2
                                // j=2 dot(meanNB,PA_k)  j=3 ||PA_k||^2
                                // j=4 rowsum(PA_k)
#define PKN 8192
#define OFF_SC  1089536         // 0:n2PA 1:n2PB 2:n2NA 3:n2NB 4:dAP 5:dBP (each [256])

__device__ __forceinline__ float dot4(float4 a, float4 b) {
    return a.x*b.x + a.y*b.y + a.z*b.z + a.w*b.w;
}
__device__ __forceinline__ float sum4(float4 a) { return a.x + a.y + a.z + a.w; }
__device__ __forceinline__ float4 add4(float4 a, float4 b) {
    return make_float4(a.x+b.x, a.y+b.y, a.z+b.z, a.w+b.w);
}

// K1: block (t,b), t=0:NA t=1:NB. Wave w reads whole k-rows (8KB contiguous).
__global__ __launch_bounds__(512) void meanNK_kernel(
    const float* __restrict__ NAp, const float* __restrict__ NBp,
    float* __restrict__ ws)
{
    const int t   = blockIdx.x >> 8;
    const int b   = blockIdx.x & 255;
    const int tid = threadIdx.x;
    const int w   = tid >> 6;
    const int l   = tid & 63;

    const float4* src = (const float4*)((t ? NBp : NAp) + (size_t)b * KSNIP * CH);

    float4 cs[8];
    #pragma unroll
    for (int j = 0; j < 8; ++j) cs[j] = make_float4(0.f,0.f,0.f,0.f);

    #pragma unroll
    for (int kk = 0; kk < 4; ++kk) {
        const int k = w + kk*8;
        float4 v[8];
        #pragma unroll
        for (int j = 0; j < 8; ++j) v[j] = src[k*CH4 + l + j*64];
        #pragma unroll
        for (int j = 0; j < 8; ++j) cs[j] = add4(cs[j], v[j]);
    }

    __shared__ float4 sCol[CH4];
    __shared__ float  sW[8];
    for (int wv = 0; wv < 8; ++wv) {
        if (w == wv) {
            #pragma unroll
            for (int j = 0; j < 8; ++j) {
                const int c = l + j*64;
                sCol[c] = (wv == 0) ? cs[j] : add4(sCol[c], cs[j]);
            }
        }
        __syncthreads();
    }

    float4 m = sCol[tid];
    const float s = 1.0f/32.0f;
    m.x *= s; m.y *= s; m.z *= s; m.w *= s;
    ((float4*)(ws + (t ? OFF_MNB : OFF_MNA) + b*CH))[tid] = m;

    float v2 = dot4(m, m);
    #pragma unroll
    for (int o = 32; o; o >>= 1) v2 += __shfl_xor(v2, o);
    if (l == 0) sW[w] = v2;
    __syncthreads();
    if (tid == 0) {
        float tot = 0.f;
        #pragma unroll
        for (int i = 0; i < 8; ++i) tot += sW[i];
        ws[OFF_SC + (2 + t)*256 + b] = tot;   // 2:n2NA 3:n2NB
    }
}

// K2: block (t,b), t=0:PA t=1:PB. Per-k dots + column k-sums.
__global__ __launch_bounds__(512) void dots_kernel(
    const float* __restrict__ PA, const float* __restrict__ PB,
    float* __restrict__ ws)
{
    const int t   = blockIdx.x >> 8;
    const int b   = blockIdx.x & 255;
    const int tid = threadIdx.x;
    const int w   = tid >> 6;
    const int l   = tid & 63;

    const float4* src = (const float4*)((t ? PB : PA) + (size_t)b * KSNIP * CH);

    __shared__ float4 sDot[CH4];   // PA->meanNB, PB->meanNA
    __shared__ float4 sDap[CH4];   // PA->meanNA, PB->meanNB
    __shared__ float4 sCol[CH4];
    __shared__ float  sW[8][2];

    sDot[tid] = ((const float4*)(ws + (t ? OFF_MNA : OFF_MNB)))[b*CH4 + tid];
    sDap[tid] = ((const float4*)(ws + (t ? OFF_MNB : OFF_MNA)))[b*CH4 + tid];
    __syncthreads();

    float4 cs[8];
    #pragma unroll
    for (int j = 0; j < 8; ++j) cs[j] = make_float4(0.f,0.f,0.f,0.f);

    #pragma unroll
    for (int kk = 0; kk < 4; ++kk) {
        const int k = w + kk*8;
        float4 v[8];
        #pragma unroll
        for (int j = 0; j < 8; ++j) v[j] = src[k*CH4 + l + j*64];

        float dq = 0.f, sq = 0.f, rs = 0.f;
        #pragma unroll
        for (int j = 0; j < 8; ++j) {
            cs[j] = add4(cs[j], v[j]);
            float4 om = sDot[l + j*64];
            dq += dot4(om, v[j]);
            sq += dot4(v[j], v[j]);
            rs += sum4(v[j]);
        }
        #pragma unroll
        for (int o = 32; o; o >>= 1) {
            dq += __shfl_xor(dq, o);
            sq += __shfl_xor(sq, o);
            rs += __shfl_xor(rs, o);
        }
        if (l == 0) {
            const int idx = k*BATCH + b;   // K-MAJOR
            if (t == 0) {   // PA
                ws[OFF_PK + 2*PKN + idx] = dq;
                ws[OFF_PK + 3*PKN + idx] = sq;
                ws[OFF_PK + 4*PKN + idx] = rs;
            } else {        // PB
                ws[OFF_PK + 0*PKN + idx] = dq;
                ws[OFF_PK + 1*PKN + idx] = sq;
            }
        }
    }

    for (int wv = 0; wv < 8; ++wv) {
        if (w == wv) {
            #pragma unroll
            for (int j = 0; j < 8; ++j) {
                const int c = l + j*64;
                sCol[c] = (wv == 0) ? cs[j] : add4(sCol[c], cs[j]);
            }
        }
        __syncthreads();
    }

    float4 m = sCol[tid];
    const float s = 1.0f/32.0f;
    m.x *= s; m.y *= s; m.z *= s; m.w *= s;
    float n2  = dot4(m, m);
    float dap = dot4(sDap[tid], m);
    #pragma unroll
    for (int o = 32; o; o >>= 1) {
        n2  += __shfl_xor(n2, o);
        dap += __shfl_xor(dap, o);
    }
    if (l == 0) { sW[w][0] = n2; sW[w][1] = dap; }
    __syncthreads();
    if (tid == 0) {
        float t0 = 0.f, t1 = 0.f;
        #pragma unroll
        for (int i = 0; i < 8; ++i) { t0 += sW[i][0]; t1 += sW[i][1]; }
        ws[OFF_SC + t*256 + b]       = t0;   // 0:n2PA 1:n2PB
        ws[OFF_SC + (4 + t)*256 + b] = t1;   // 4:dAP  5:dBP
    }
}

// K3: single block, 256 threads (thread == video b). Latency-optimized finish.
__global__ __launch_bounds__(256) void finish_kernel(
    const float* __restrict__ vs, const float* __restrict__ label,
    const float* __restrict__ ws, float* __restrict__ out)
{
    const int tid  = threadIdx.x;
    const int b    = tid;
    const int lane = tid & 63;
    const int w    = tid >> 6;

    __shared__ float sLab[NCLSS*BATCH];           // [c][b]
    __shared__ float sVS [NCLSS*BATCH];           // [c][b]
    __shared__ float an[BATCH][33];
    __shared__ float sD[NCLSS][BATCH];
    __shared__ unsigned long long sMask[NCLSS][4];
    __shared__ int   sAnchor[NCLSS];
    __shared__ int   sCnt[NCLSS];
    __shared__ float sbuf[4];
    __shared__ float stp[4];

    const float* pk = ws + OFF_PK;

    // ---- stage label/vs transposed + an rows into LDS (coalesced) ----
    #pragma unroll
    for (int j = 0; j < NCLSS; ++j) {
        const int i = j*BATCH + tid;
        const int c = i % NCLSS;
        const int bb = i / NCLSS;
        sLab[c*BATCH + bb] = label[i];
        sVS [c*BATCH + bb] = vs[i];
    }
    #pragma unroll
    for (int j = 0; j < KSNIP; ++j) {
        const int i = j*BATCH + tid;       // k-major: k=i>>8, b=i&255
        an[i & 255][i >> 8] = pk[4*PKN + i];
    }
    __syncthreads();

    // ---- normalize an row b ----
    {
        float nrm = 0.f;
        #pragma unroll
        for (int k = 0; k < KSNIP; ++k) { float v = an[b][k]; nrm += v*v; }
        const float inv = 1.0f / sqrtf(nrm);
        #pragma unroll
        for (int k = 0; k < KSNIP; ++k) an[b][k] *= inv;
    }

    // ---- per-b scalar losses ----
    const float invT = 1.0f / 0.07f;
    const float nPA = sqrtf(ws[OFF_SC + 0*256 + b]);
    const float nPB = sqrtf(ws[OFF_SC + 1*256 + b]);
    const float nNA = sqrtf(ws[OFF_SC + 2*256 + b]);
    const float nNB = sqrtf(ws[OFF_SC + 3*256 + b]);
    const float dAP = ws[OFF_SC + 4*256 + b];
    const float dBP = ws[OFF_SC + 5*256 + b];

    float nce;
    {   // NCE 1: q=meanNA, neg=PB
        const float lpos = dAP / (nNA * nPA) * invT;
        float vv[KSNIP];
        #pragma unroll
        for (int k = 0; k < KSNIP; ++k) {
            const float dq = pk[0*PKN + k*BATCH + b];
            const float sq = pk[1*PKN + k*BATCH + b];
            vv[k] = dq * invT / (nNA * sqrtf(sq));
        }
        float m = lpos;
        #pragma unroll
        for (int k = 0; k < KSNIP; ++k) m = fmaxf(m, vv[k]);
        float s = expf(lpos - m);
        #pragma unroll
        for (int k = 0; k < KSNIP; ++k) s += expf(vv[k] - m);
        nce = logf(s) + m - lpos;
    }
    {   // NCE 2: q=meanNB, neg=PA
        const float lpos = dBP / (nNB * nPB) * invT;
        float vv[KSNIP];
        #pragma unroll
        for (int k = 0; k < KSNIP; ++k) {
            const float dq = pk[2*PKN + k*BATCH + b];
            const float sq = pk[3*PKN + k*BATCH + b];
            vv[k] = dq * invT / (nNB * sqrtf(sq));
        }
        float m = lpos;
        #pragma unroll
        for (int k = 0; k < KSNIP; ++k) m = fmaxf(m, vv[k]);
        float s = expf(lpos - m);
        #pragma unroll
        for (int k = 0; k < KSNIP; ++k) s += expf(vv[k] - m);
        nce += logf(s) + m - lpos;
    }

    const float la   = fmaxf(150.0f - nPA, 0.0f);
    const float absb = (la + nPB) * (la + nPB);

    float rs = 0.0f;
    #pragma unroll
    for (int c = 0; c < NCLSS; ++c) rs += sLab[c*BATCH + b];
    float clsb = 0.0f;
    #pragma unroll
    for (int c = 0; c < NCLSS; ++c) {
        const float l = sLab[c*BATCH + b] / rs;
        const float p = sVS [c*BATCH + b];
        clsb -= l * logf(p) + (1.0f - l) * logf(1.0f - p);
    }

    auto blocksum = [&](float v) -> float {
        #pragma unroll
        for (int o = 32; o; o >>= 1) v += __shfl_xor(v, o);
        __syncthreads();
        if (lane == 0) sbuf[w] = v;
        __syncthreads();
        return sbuf[0] + sbuf[1] + sbuf[2] + sbuf[3];
    };

    const float loss_snico = blocksum(nce)  / 256.0f;
    const float loss_abs   = blocksum(absb) / 256.0f;
    const float loss_cls   = blocksum(clsb) / 5120.0f;

    // ---- triplet: ballot anchors, then wave-parallel class reductions ----
    #pragma unroll
    for (int c = 0; c < NCLSS; ++c) {
        const bool mm = sLab[c*BATCH + b] > 0.5f;
        const unsigned long long mk = __ballot(mm);
        if (lane == 0) sMask[c][w] = mk;
    }
    __syncthreads();
    if (tid < NCLSS) {
        int cnt = 0, anchor = -1;
        #pragma unroll
        for (int q = 3; q >= 0; --q) {
            const unsigned long long mq = sMask[tid][q];
            cnt += __builtin_popcountll(mq);
            if (anchor < 0 && mq) anchor = q*64 + 63 - __builtin_clzll(mq);
        }
        sAnchor[tid] = anchor;
        sCnt[tid]    = cnt;
    }
    __syncthreads();

    #pragma unroll
    for (int c = 0; c < NCLSS; ++c) {
        if (sCnt[c] > 1) {
            const int a = sAnchor[c];
            float acc = 0.f;
            #pragma unroll
            for (int k = 0; k < KSNIP; ++k) acc += an[a][k] * an[b][k];
            sD[c][b] = 1.0f - acc;
        }
    }
    __syncthreads();

    float tripw = 0.f;
    #pragma unroll
    for (int cc = 0; cc < 5; ++cc) {
        const int c = w*5 + cc;
        if (sCnt[c] > 1) {
            const int a = sAnchor[c];
            float vAll = -__builtin_inff();
            float vMem = -__builtin_inff();
            float vNon =  __builtin_inff();
            #pragma unroll
            for (int q = 0; q < 4; ++q) {
                const int bb = lane + q*64;
                const float d = sD[c][bb];
                const bool mm = (sMask[c][q] >> lane) & 1ull;
                vAll = fmaxf(vAll, d);
                if (mm && bb != a) vMem = fmaxf(vMem, d);
                if (!mm)           vNon = fminf(vNon, d);
            }
            #pragma unroll
            for (int o = 32; o; o >>= 1) {
                vAll = fmaxf(vAll, __shfl_xor(vAll, o));
                vMem = fmaxf(vMem, __shfl_xor(vMem, o));
                vNon = fminf(vNon, __shfl_xor(vNon, o));
            }
            if (lane == 0) {
                const float max_d = fmaxf(0.0f, vMem);
                const float min_d = fminf(vAll, vNon);
                tripw += fmaxf(max_d - min_d + 0.8f, 0.0f);
            }
        }
    }
    if (lane == 0) stp[w] = tripw;
    __syncthreads();

    if (tid == 0) {
        const float trip_total = stp[0] + stp[1] + stp[2] + stp[3];
        const float total = loss_cls + 0.01f * loss_snico + 0.0005f * loss_abs + 0.005f * trip_total;
        out[0] = total;
        out[1] = loss_cls;
        out[2] = loss_snico;
        out[3] = loss_abs;
        out[4] = trip_total;
    }
}

extern "C" void kernel_launch(void* const* d_in, const int* in_sizes, int n_in,
                              void* d_out, int out_size, void* d_ws, size_t ws_size,
                              hipStream_t stream) {
    const float* vs    = (const float*)d_in[0];
    const float* label = (const float*)d_in[1];
    const float* PA    = (const float*)d_in[2];
    const float* PB    = (const float*)d_in[3];
    const float* NAp   = (const float*)d_in[4];
    const float* NBp   = (const float*)d_in[5];
    float* ws  = (float*)d_ws;
    float* out = (float*)d_out;

    meanNK_kernel<<<dim3(512), dim3(512), 0, stream>>>(NAp, NBp, ws);
    dots_kernel  <<<dim3(512), dim3(512), 0, stream>>>(PA, PB, ws);
    finish_kernel<<<dim3(1),   dim3(256), 0, stream>>>(vs, label, ws, out);
}